// Round 6
// baseline (518.773 us; speedup 1.0000x reference)
//
#include <hip/hip_runtime.h>
#include <math.h>

#define NB_PER_BLOCK 16   // batches per 256-thread block (4 per wave)

// Layout:
//  phase 1: 16 lanes per batch scan the 128 occupancy ints -> sorted lists of
//           the 32 occupied k (up: slots 0..15 hold k in [0,64), dn: 16..31 hold k in [64,128)).
//  phase 2: 8 lanes per 16x16 matrix (2 rows per lane: s8 and s8+8). Each wave
//           builds 8 matrices (4 batches). Entry = sum over the batch's 32
//           occupied k of W[k, r*32 + m*16 + j]; each lane reads one aligned
//           64B line per (row,k) as 4x float4.
//  phase 3: LU with implicit partial pivoting inside each 8-lane group
//           (lexicographic tie-break keeps the pivot wave-uniform).
//           log|det| = sum log|pivot|; sign parity = (#neg pivots +
//           permutation inversions) mod 2.
//  output:  PLANAR complex serialization (R4 experiment, retried after R5
//           infra flake): out[b] = re, out[B+b] = im. The interleaved (B,2)
//           attempt failed deterministically with absmax 14.9 > max|ref| —
//           the cross-index signature of a layout permutation.

__global__ __launch_bounds__(256) void backflow_kernel(
    const int* __restrict__ nocc,   // (B,128) int32 0/1
    const float* __restrict__ W,    // (128,2048) f32 row-major
    float* __restrict__ out,        // planar: [B re][B im]
    int B)
{
    __shared__ int lists[NB_PER_BLOCK][33];  // padded to 33 to break bank aliasing

    const int tid = threadIdx.x;

    // ---------------- phase 1: occupancy -> k lists ----------------
    {
        const int bib1 = tid >> 4;                 // 0..15
        const int l16  = tid & 15;
        int batch1 = blockIdx.x * NB_PER_BLOCK + bib1;
        if (batch1 >= B) batch1 = B - 1;           // clamp (B is a multiple of 16 anyway)
        const int4* np = reinterpret_cast<const int4*>(nocc + (size_t)batch1 * 128 + l16 * 8);
        int4 v0 = np[0];
        int4 v1 = np[1];
        unsigned nib = 0;
        nib |= (v0.x != 0) ? 1u   : 0u;
        nib |= (v0.y != 0) ? 2u   : 0u;
        nib |= (v0.z != 0) ? 4u   : 0u;
        nib |= (v0.w != 0) ? 8u   : 0u;
        nib |= (v1.x != 0) ? 16u  : 0u;
        nib |= (v1.y != 0) ? 32u  : 0u;
        nib |= (v1.z != 0) ? 64u  : 0u;
        nib |= (v1.w != 0) ? 128u : 0u;
        const int cnt = __popc(nib);
        int incl = cnt;
        const int seg = l16 & 7;                   // lane within 8-lane segment (up / dn)
        #pragma unroll
        for (int d = 1; d < 8; d <<= 1) {
            int t = __shfl_up(incl, d, 8);
            if (seg >= d) incl += t;
        }
        int pos = ((l16 >> 3) << 4) + (incl - cnt);  // spin*16 + exclusive prefix
        const int k0 = l16 * 8;                      // absolute k of bit 0
        #pragma unroll
        for (int b = 0; b < 8; b++) {
            if (nib & (1u << b)) lists[bib1][pos++] = k0 + b;
        }
    }
    __syncthreads();

    // ---------------- phase 2: build two rows per lane ----------------
    const int lane = tid & 63;
    const int wave = tid >> 6;
    const int g    = lane >> 3;         // matrix group in wave 0..7
    const int s8   = lane & 7;          // lane in group
    const int bw   = g >> 1;            // batch in wave 0..3
    const int m    = g & 1;             // 0 = up, 1 = dn
    const int bib  = (wave << 2) + bw;
    int batch = blockIdx.x * NB_PER_BLOCK + bib;
    const bool valid = (batch < B);
    if (batch >= B) batch = B - 1;

    const int r0 = lists[bib][(m << 4) + s8]     - (m << 6);
    const int r1 = lists[bib][(m << 4) + s8 + 8] - (m << 6);
    const float* w0 = W + r0 * 32 + m * 16;   // 64B-aligned line per (row,k)
    const float* w1 = W + r1 * 32 + m * 16;

    float a0[16], a1[16];
    #pragma unroll
    for (int j = 0; j < 16; j++) { a0[j] = 0.f; a1[j] = 0.f; }

    #pragma unroll 1
    for (int t = 0; t < 32; t++) {
        const int k = lists[bib][t];
        const float4* p0 = reinterpret_cast<const float4*>(w0 + (size_t)k * 2048);
        const float4* p1 = reinterpret_cast<const float4*>(w1 + (size_t)k * 2048);
        float4 u0 = p0[0], u1 = p0[1], u2 = p0[2], u3 = p0[3];
        float4 q0 = p1[0], q1 = p1[1], q2 = p1[2], q3 = p1[3];
        a0[0]+=u0.x;  a0[1]+=u0.y;  a0[2]+=u0.z;  a0[3]+=u0.w;
        a0[4]+=u1.x;  a0[5]+=u1.y;  a0[6]+=u1.z;  a0[7]+=u1.w;
        a0[8]+=u2.x;  a0[9]+=u2.y;  a0[10]+=u2.z; a0[11]+=u2.w;
        a0[12]+=u3.x; a0[13]+=u3.y; a0[14]+=u3.z; a0[15]+=u3.w;
        a1[0]+=q0.x;  a1[1]+=q0.y;  a1[2]+=q0.z;  a1[3]+=q0.w;
        a1[4]+=q1.x;  a1[5]+=q1.y;  a1[6]+=q1.z;  a1[7]+=q1.w;
        a1[8]+=q2.x;  a1[9]+=q2.y;  a1[10]+=q2.z; a1[11]+=q2.w;
        a1[12]+=q3.x; a1[13]+=q3.y; a1[14]+=q3.z; a1[15]+=q3.w;
    }

    // ---------------- phase 3: LU, implicit partial pivoting ----------------
    unsigned active = 0xffffu;   // rows not yet chosen as pivot (uniform in group)
    int inv = 0;                 // permutation inversion count (uniform)
    float myd0 = 1.f, myd1 = 1.f;

    #pragma unroll
    for (int k = 0; k < 16; k++) {
        const unsigned act0 = (active >> s8) & 1u;
        const unsigned act1 = (active >> (s8 + 8)) & 1u;
        float av = act0 ? fabsf(a0[k]) : -1.f;
        int idx = s8;
        {
            float av1 = act1 ? fabsf(a1[k]) : -1.f;
            if (av1 > av) { av = av1; idx = s8 + 8; }   // tie keeps smaller idx
        }
        // butterfly max with LEXICOGRAPHIC tie-break -> (max av, min idx), uniform
        #pragma unroll
        for (int d = 1; d < 8; d <<= 1) {
            float ov = __shfl_xor(av, d, 8);
            int   oi = __shfl_xor(idx, d, 8);
            if (ov > av || (ov == av && oi < idx)) { av = ov; idx = oi; }
        }
        const int p = idx;                        // uniform in group
        const int plane = p & 7;
        const bool phi = (p & 8) != 0;            // pivot row lives in a1 half
        float psel = phi ? a1[k] : a0[k];
        const float pk = __shfl(psel, plane, 8);  // signed pivot value
        const float rcp = 1.0f / pk;              // exact IEEE divide (cheap: 16/matrix)

        if (s8 == p)     myd0 = pk;
        if (s8 + 8 == p) myd1 = pk;
        inv += __popc(active & ((1u << p) - 1u));
        active &= ~(1u << p);

        const float f0 = (act0 && s8 != p)       ? a0[k] * rcp : 0.f;
        const float f1 = (act1 && (s8 + 8) != p) ? a1[k] * rcp : 0.f;

        #pragma unroll
        for (int j = k + 1; j < 16; j++) {
            float sel = phi ? a1[j] : a0[j];
            float pv = __shfl(sel, plane, 8);
            a0[j] = fmaf(-f0, pv, a0[j]);
            a1[j] = fmaf(-f1, pv, a1[j]);
        }
    }

    // per-lane: two diagonal entries -> log-sum + sign count, butterfly over 8 lanes
    float ld = logf(fabsf(myd0)) + logf(fabsf(myd1));
    int ng = ((myd0 < 0.f) ? 1 : 0) + ((myd1 < 0.f) ? 1 : 0);
    #pragma unroll
    for (int d = 1; d < 8; d <<= 1) {
        ld += __shfl_xor(ld, d, 8);
        ng += __shfl_xor(ng, d, 8);
    }
    const int neg = (ng + inv) & 1;

    // combine up (even group) with dn (odd group)
    const float ld_o  = __shfl_xor(ld, 8, 16);
    const int   neg_o = __shfl_xor(neg, 8, 16);

    if ((lane & 15) == 0 && valid) {
        out[batch]     = ld + ld_o;                                      // re plane
        out[B + batch] = 3.14159265358979323846f * (float)(neg + neg_o); // im plane
    }
}

extern "C" void kernel_launch(void* const* d_in, const int* in_sizes, int n_in,
                              void* d_out, int out_size, void* d_ws, size_t ws_size,
                              hipStream_t stream) {
    const int* nocc = (const int*)d_in[0];
    const float* W  = (const float*)d_in[1];
    float* out = (float*)d_out;
    const int B = in_sizes[0] / 128;                      // 65536
    const int blocks = (B + NB_PER_BLOCK - 1) / NB_PER_BLOCK;  // 4096
    backflow_kernel<<<blocks, 256, 0, stream>>>(nocc, W, out, B);
}

// Round 7
// 318.881 us; speedup vs baseline: 1.6269x; 1.6269x over previous
//
#include <hip/hip_runtime.h>
#include <math.h>

#define NB_PER_BLOCK 16   // batches per 256-thread block
#define ROWSTRIDE 20      // A-row stride in LDS floats (16 data + 4 pad: 16B-aligned, banks spread)
#define MATSTRIDE 644     // per-batch stride (32*20 + 4): +4 skews batches across banks for LU reads

// phase 1: 16 lanes/batch scan 128 occupancy ints -> sorted occupied-k lists
//          (slots 0..15: up k in [0,64); 16..31: dn k in [64,128)).
// phase 2: cooperative gather. 4 lanes own one (batch, A-row): each lane reads
//          ONE float4 (quarter row) per occupied k -> one dwordx4 per 64B line
//          touch (the old layout did 4 separate loads of the same line -> 4x
//          L1 line-accesses; measured 70 cyc/load-inst = L1 line-pipe bound).
//          Accumulate over 32 k, write quarter-rows to LDS amat.
// phase 3: unchanged 8-lane LU with implicit partial pivoting (lexicographic
//          tie-break), rows read back from amat. log|det| = sum log|pivot|,
//          sign parity = (#neg pivots + inversions) mod 2.
// output:  planar complex: out[b] = re, out[B+b] = im.  (verified R6)

__global__ __launch_bounds__(256) void backflow_kernel(
    const int* __restrict__ nocc,   // (B,128) int32 0/1
    const float* __restrict__ W,    // (128,2048) f32 row-major
    float* __restrict__ out,        // planar: [B re][B im]
    int B)
{
    __shared__ int lists[NB_PER_BLOCK][33];
    __shared__ float amat[NB_PER_BLOCK * MATSTRIDE];   // ~41.2 KB

    const int tid = threadIdx.x;

    // ---------------- phase 1: occupancy -> k lists ----------------
    {
        const int bib1 = tid >> 4;                 // 0..15
        const int l16  = tid & 15;
        int batch1 = blockIdx.x * NB_PER_BLOCK + bib1;
        if (batch1 >= B) batch1 = B - 1;
        const int4* np = reinterpret_cast<const int4*>(nocc + (size_t)batch1 * 128 + l16 * 8);
        int4 v0 = np[0];
        int4 v1 = np[1];
        unsigned nib = 0;
        nib |= (v0.x != 0) ? 1u   : 0u;
        nib |= (v0.y != 0) ? 2u   : 0u;
        nib |= (v0.z != 0) ? 4u   : 0u;
        nib |= (v0.w != 0) ? 8u   : 0u;
        nib |= (v1.x != 0) ? 16u  : 0u;
        nib |= (v1.y != 0) ? 32u  : 0u;
        nib |= (v1.z != 0) ? 64u  : 0u;
        nib |= (v1.w != 0) ? 128u : 0u;
        const int cnt = __popc(nib);
        int incl = cnt;
        const int seg = l16 & 7;
        #pragma unroll
        for (int d = 1; d < 8; d <<= 1) {
            int t = __shfl_up(incl, d, 8);
            if (seg >= d) incl += t;
        }
        int pos = ((l16 >> 3) << 4) + (incl - cnt);
        const int k0 = l16 * 8;
        #pragma unroll
        for (int b = 0; b < 8; b++) {
            if (nib & (1u << b)) lists[bib1][pos++] = k0 + b;
        }
    }
    __syncthreads();

    // ---------------- phase 2: cooperative gather (4 lanes per A-row) ----------------
    {
        const int q = tid & 3;          // quarter within row
        const int G = tid >> 2;         // row-group 0..63
        #pragma unroll 1
        for (int p = 0; p < 8; p++) {
            const int rowflat = p * 64 + G;        // 0..511 = bib*32 + ridx
            const int bib2 = rowflat >> 5;
            const int ridx = rowflat & 31;         // 0..15 up, 16..31 dn
            const int m2 = ridx >> 4;
            const int r = lists[bib2][ridx] - (m2 << 6);
            const float* wp = W + r * 32 + m2 * 16 + q * 4;
            float4 acc = {0.f, 0.f, 0.f, 0.f};
            #pragma unroll 8
            for (int t = 0; t < 32; t++) {
                const int k = lists[bib2][t];
                const float4 v = *reinterpret_cast<const float4*>(wp + (size_t)k * 2048);
                acc.x += v.x; acc.y += v.y; acc.z += v.z; acc.w += v.w;
            }
            *reinterpret_cast<float4*>(&amat[bib2 * MATSTRIDE + ridx * ROWSTRIDE + q * 4]) = acc;
        }
    }
    __syncthreads();

    // ---------------- phase 3: LU, implicit partial pivoting ----------------
    const int lane = tid & 63;
    const int wave = tid >> 6;
    const int g    = lane >> 3;         // matrix group in wave 0..7
    const int s8   = lane & 7;          // lane in group
    const int bw   = g >> 1;            // batch in wave 0..3
    const int m    = g & 1;             // 0 = up, 1 = dn
    const int bib  = (wave << 2) + bw;
    int batch = blockIdx.x * NB_PER_BLOCK + bib;
    const bool valid = (batch < B);
    if (batch >= B) batch = B - 1;

    float a0[16], a1[16];
    {
        const float* row0 = &amat[bib * MATSTRIDE + (m * 16 + s8) * ROWSTRIDE];
        const float* row1 = row0 + 8 * ROWSTRIDE;
        #pragma unroll
        for (int qq = 0; qq < 4; qq++) {
            float4 v0 = *reinterpret_cast<const float4*>(row0 + qq * 4);
            float4 v1 = *reinterpret_cast<const float4*>(row1 + qq * 4);
            a0[qq*4+0] = v0.x; a0[qq*4+1] = v0.y; a0[qq*4+2] = v0.z; a0[qq*4+3] = v0.w;
            a1[qq*4+0] = v1.x; a1[qq*4+1] = v1.y; a1[qq*4+2] = v1.z; a1[qq*4+3] = v1.w;
        }
    }

    unsigned active = 0xffffu;
    int inv = 0;
    float myd0 = 1.f, myd1 = 1.f;

    #pragma unroll
    for (int k = 0; k < 16; k++) {
        const unsigned act0 = (active >> s8) & 1u;
        const unsigned act1 = (active >> (s8 + 8)) & 1u;
        float av = act0 ? fabsf(a0[k]) : -1.f;
        int idx = s8;
        {
            float av1 = act1 ? fabsf(a1[k]) : -1.f;
            if (av1 > av) { av = av1; idx = s8 + 8; }
        }
        #pragma unroll
        for (int d = 1; d < 8; d <<= 1) {
            float ov = __shfl_xor(av, d, 8);
            int   oi = __shfl_xor(idx, d, 8);
            if (ov > av || (ov == av && oi < idx)) { av = ov; idx = oi; }
        }
        const int p = idx;
        const int plane = p & 7;
        const bool phi = (p & 8) != 0;
        float psel = phi ? a1[k] : a0[k];
        const float pk = __shfl(psel, plane, 8);
        const float rcp = 1.0f / pk;

        if (s8 == p)     myd0 = pk;
        if (s8 + 8 == p) myd1 = pk;
        inv += __popc(active & ((1u << p) - 1u));
        active &= ~(1u << p);

        const float f0 = (act0 && s8 != p)       ? a0[k] * rcp : 0.f;
        const float f1 = (act1 && (s8 + 8) != p) ? a1[k] * rcp : 0.f;

        #pragma unroll
        for (int j = k + 1; j < 16; j++) {
            float sel = phi ? a1[j] : a0[j];
            float pv = __shfl(sel, plane, 8);
            a0[j] = fmaf(-f0, pv, a0[j]);
            a1[j] = fmaf(-f1, pv, a1[j]);
        }
    }

    float ld = logf(fabsf(myd0)) + logf(fabsf(myd1));
    int ng = ((myd0 < 0.f) ? 1 : 0) + ((myd1 < 0.f) ? 1 : 0);
    #pragma unroll
    for (int d = 1; d < 8; d <<= 1) {
        ld += __shfl_xor(ld, d, 8);
        ng += __shfl_xor(ng, d, 8);
    }
    const int neg = (ng + inv) & 1;

    const float ld_o  = __shfl_xor(ld, 8, 16);
    const int   neg_o = __shfl_xor(neg, 8, 16);

    if ((lane & 15) == 0 && valid) {
        out[batch]     = ld + ld_o;                                      // re plane
        out[B + batch] = 3.14159265358979323846f * (float)(neg + neg_o); // im plane
    }
}

extern "C" void kernel_launch(void* const* d_in, const int* in_sizes, int n_in,
                              void* d_out, int out_size, void* d_ws, size_t ws_size,
                              hipStream_t stream) {
    const int* nocc = (const int*)d_in[0];
    const float* W  = (const float*)d_in[1];
    float* out = (float*)d_out;
    const int B = in_sizes[0] / 128;                      // 65536
    const int blocks = (B + NB_PER_BLOCK - 1) / NB_PER_BLOCK;  // 4096
    backflow_kernel<<<blocks, 256, 0, stream>>>(nocc, W, out, B);
}